// Round 9
// baseline (1711.680 us; speedup 1.0000x reference)
//
#include <hip/hip_runtime.h>
#include <hip/hip_bf16.h>
#include <math.h>

// ---- problem constants ----
#define BATCH   8
#define C_IN    3
#define IMG_SZ  224
#define P_SZ    16
#define NPATCH  196                 // (224/16)^2
#define MSEQ    197                 // NPATCH + cls
#define DDIM    192
#define EDIM    384
#define NSTATE  16
#define ENDIM   (EDIM*NSTATE)       // 6144
#define LLAYERS 2
#define ROWS    (BATCH*MSEQ)        // 1576
#define PROWS   (BATCH*NPATCH)      // 1568
#define PATCH_K (C_IN*P_SZ*P_SZ)    // 768

// precise silu (enters the scan only linearly)
__device__ __forceinline__ float silu_f(float x) { return x / (1.f + expf(-x)); }

// ------------------------------------------------------------------
// patchify: img (B,3,224,224) -> patches (PROWS, 768)
// ------------------------------------------------------------------
__global__ __launch_bounds__(256) void patchify_k(const float* __restrict__ img,
                                                  float* __restrict__ out) {
    int idx = blockIdx.x * 256 + threadIdx.x;
    if (idx >= PROWS * PATCH_K) return;
    int r = idx / PATCH_K, col = idx - r * PATCH_K;
    int b = r / NPATCH, p = r - b * NPATCH;
    int ph = p / 14, pw = p - ph * 14;
    int c = col >> 8, rem = col & 255, py = rem >> 4, px = rem & 15;
    out[idx] = img[((b * C_IN + c) * IMG_SZ + ph * P_SZ + py) * IMG_SZ + pw * P_SZ + px];
}

// ------------------------------------------------------------------
// assemble x = concat(cls, xemb) + pos   -> (B, MSEQ, DDIM)
// ------------------------------------------------------------------
__global__ __launch_bounds__(256) void assemble_k(const float* __restrict__ xemb,
                                                  const float* __restrict__ cls,
                                                  const float* __restrict__ pos,
                                                  float* __restrict__ x) {
    int idx = blockIdx.x * 256 + threadIdx.x;
    if (idx >= ROWS * DDIM) return;
    int d = idx % DDIM;
    int bm = idx / DDIM;
    int m = bm % MSEQ, b = bm / MSEQ;
    float v;
    if (m == 0) v = cls[d];
    else        v = xemb[((b * NPATCH) + (m - 1)) * DDIM + d];
    x[idx] = v + pos[m * DDIM + d];
}

// ------------------------------------------------------------------
// layernorm over last dim (DDIM=192), one wave per row
// ------------------------------------------------------------------
__global__ __launch_bounds__(256) void layernorm_k(const float* __restrict__ x,
                                                   const float* __restrict__ g,
                                                   const float* __restrict__ b,
                                                   float* __restrict__ o, int nrows) {
    int wave = threadIdx.x >> 6;
    int lane = threadIdx.x & 63;
    int row = blockIdx.x * 4 + wave;
    if (row >= nrows) return;
    const float* xr = x + (long)row * DDIM;
    float v0 = xr[lane], v1 = xr[lane + 64], v2 = xr[lane + 128];
    float s = v0 + v1 + v2;
    #pragma unroll
    for (int off = 1; off < 64; off <<= 1) s += __shfl_xor(s, off);
    float mu = s * (1.f / 192.f);
    float d0 = v0 - mu, d1 = v1 - mu, d2 = v2 - mu;
    float q = d0 * d0 + d1 * d1 + d2 * d2;
    #pragma unroll
    for (int off = 1; off < 64; off <<= 1) q += __shfl_xor(q, off);
    float inv = rsqrtf(q * (1.f / 192.f) + 1e-5f);
    float* orow = o + (long)row * DDIM;
    orow[lane]       = d0 * inv * g[lane]       + b[lane];
    orow[lane + 64]  = d1 * inv * g[lane + 64]  + b[lane + 64];
    orow[lane + 128] = d2 * inv * g[lane + 128] + b[lane + 128];
}

// ------------------------------------------------------------------
// BIG fp32 GEMM, 128x128 tile, 8x8/thread, SINGLE-buffer LDS with
// REGISTER-STAGED prefetch: issue next tile's global loads, compute
// current tile (hides HBM/L2 latency), barrier, write regs->LDS,
// barrier. LDS 16.9KB, VGPR ~64.
// gridDim.z=2 ONLY (z=4 thrashes L2: 37.6MB of W panels > 32MB agg L2
// -> 30x W over-fetch, round-8 lesson). z=2 keeps W L2-resident AND
// y-sharing blocks land on the same XCD (id stride 48 % 8 == 0).
// ------------------------------------------------------------------
#define BM 128
#define BK 16
__global__ __launch_bounds__(256, 4) void gemm_big(
        const float* __restrict__ A,
        const float* __restrict__ W0, const float* __restrict__ b0, float* __restrict__ C0,
        const float* __restrict__ W1, const float* __restrict__ b1, float* __restrict__ C1,
        int M, int N, int K) {
    int z = blockIdx.z;
    const float* W    = z ? W1 : W0;
    const float* bias = z ? b1 : b0;
    float*       C    = z ? C1 : C0;
    __shared__ float As[BK][BM + 4];
    __shared__ float Ws[2][BK][64];
    int t = threadIdx.x;
    int tx = t & 15, ty = t >> 4;
    long colBase = (long)blockIdx.x * 128;
    int rowBase = blockIdx.y * BM;
    float acc[8][8] = {};
    int a_m = t >> 1, a_k = (t & 1) << 3;      // A: 2 float4 per thread
    int w_k = t >> 4, w_n = (t & 15) << 2;     // W: 1 float4 per panel per thread
    int ar = rowBase + a_m;
    const float* aptr = &A[(long)ar * K + a_k];

    float4 rv0, rv1, ru0, ru1;                 // staging registers
    auto gload = [&](int k0) {
        rv0 = make_float4(0.f,0.f,0.f,0.f); rv1 = rv0;
        if (ar < M) { rv0 = *(const float4*)(aptr + k0); rv1 = *(const float4*)(aptr + k0 + 4); }
        ru0 = *(const float4*)&W[(long)(k0 + w_k) * N + colBase + w_n];
        ru1 = *(const float4*)&W[(long)(k0 + w_k) * N + colBase + 64 + w_n];
    };
    auto stage = [&]() {
        As[a_k + 0][a_m] = rv0.x; As[a_k + 1][a_m] = rv0.y;
        As[a_k + 2][a_m] = rv0.z; As[a_k + 3][a_m] = rv0.w;
        As[a_k + 4][a_m] = rv1.x; As[a_k + 5][a_m] = rv1.y;
        As[a_k + 6][a_m] = rv1.z; As[a_k + 7][a_m] = rv1.w;
        *(float4*)&Ws[0][w_k][w_n] = ru0;
        *(float4*)&Ws[1][w_k][w_n] = ru1;
    };
    auto compute = [&]() {
        #pragma unroll
        for (int kk = 0; kk < BK; ++kk) {
            float4 a0 = *(const float4*)&As[kk][ty << 3];
            float4 a1 = *(const float4*)&As[kk][(ty << 3) + 4];
            float ar8[8] = {a0.x, a0.y, a0.z, a0.w, a1.x, a1.y, a1.z, a1.w};
            #pragma unroll
            for (int hh = 0; hh < 2; ++hh) {
                float4 w = *(const float4*)&Ws[hh][kk][tx << 2];
                float wr[4] = {w.x, w.y, w.z, w.w};
                #pragma unroll
                for (int i = 0; i < 8; ++i)
                    #pragma unroll
                    for (int j = 0; j < 4; ++j)
                        acc[i][hh * 4 + j] += ar8[i] * wr[j];
            }
        }
    };

    gload(0);
    stage();
    __syncthreads();
    int nt = K / BK;
    for (int kt = 1; kt < nt; ++kt) {
        gload(kt * BK);          // in flight during compute
        compute();
        __syncthreads();         // all readers done with LDS
        stage();                 // vmcnt(0) lands here, after compute
        __syncthreads();
    }
    compute();

    #pragma unroll
    for (int i = 0; i < 8; ++i) {
        int r = rowBase + (ty << 3) + i;
        if (r >= M) break;
        #pragma unroll
        for (int hh = 0; hh < 2; ++hh) {
            long cb = colBase + hh * 64 + (tx << 2);
            float4 o;
            o.x = acc[i][hh * 4 + 0] + bias[cb + 0];
            o.y = acc[i][hh * 4 + 1] + bias[cb + 1];
            o.z = acc[i][hh * 4 + 2] + bias[cb + 2];
            o.w = acc[i][hh * 4 + 3] + bias[cb + 3];
            *(float4*)&C[(long)r * N + cb] = o;
        }
    }
}

// ------------------------------------------------------------------
// SMALL fp32 GEMM: one WAVE per 32x32 tile, 4x4/thread, double-
// buffered LDS. gridDim.z selects two independent sets (Wx+Wz, Df+Db).
// SP = correctly-rounded softplus epilogue. k-ascending FMA order.
// ------------------------------------------------------------------
#define SBK 16
template<bool SP, bool HASB2, bool HASRES>
__global__ __launch_bounds__(64) void gemm_s(const float* __restrict__ A0,
                                             const float* __restrict__ W0,
                                             const float* __restrict__ b10,
                                             const float* __restrict__ b20,
                                             const float* __restrict__ r0,
                                             float* __restrict__ C0,
                                             const float* __restrict__ A1,
                                             const float* __restrict__ W1,
                                             const float* __restrict__ b11,
                                             const float* __restrict__ b21,
                                             const float* __restrict__ r1,
                                             float* __restrict__ C1,
                                             int M, int N, int K) {
    const float* A  = blockIdx.z ? A1  : A0;
    const float* W  = blockIdx.z ? W1  : W0;
    const float* bp = blockIdx.z ? b11 : b10;
    const float* b2 = blockIdx.z ? b21 : b20;
    const float* rp = blockIdx.z ? r1  : r0;
    float*       C  = blockIdx.z ? C1  : C0;
    __shared__ float As[2][SBK][36];
    __shared__ float Wsh[2][SBK][36];
    int t = threadIdx.x;            // 0..63
    int tx = t & 7, ty = t >> 3;
    int rowBase = blockIdx.y * 32;
    long colBase = (long)blockIdx.x * 32;
    int rA = t >> 2, kqA = (t & 3) << 2;
    int kW = t >> 3, nqW = (t & 7) << 2;
    float acc[4][4] = {};
    int r0i = rowBase + rA, r1i = r0i + 16;

    auto loadA = [&](int k0, float4& a0, float4& a1) {
        a0 = make_float4(0.f,0.f,0.f,0.f); a1 = a0;
        if (r0i < M) a0 = *(const float4*)&A[(long)r0i * K + k0 + kqA];
        if (r1i < M) a1 = *(const float4*)&A[(long)r1i * K + k0 + kqA];
    };
    auto stage = [&](int buf, float4 a0, float4 a1, float4 w0, float4 w1) {
        As[buf][kqA + 0][rA] = a0.x; As[buf][kqA + 1][rA] = a0.y;
        As[buf][kqA + 2][rA] = a0.z; As[buf][kqA + 3][rA] = a0.w;
        As[buf][kqA + 0][rA + 16] = a1.x; As[buf][kqA + 1][rA + 16] = a1.y;
        As[buf][kqA + 2][rA + 16] = a1.z; As[buf][kqA + 3][rA + 16] = a1.w;
        *(float4*)&Wsh[buf][kW][nqW]     = w0;
        *(float4*)&Wsh[buf][kW + 8][nqW] = w1;
    };
    auto compute = [&](int buf) {
        #pragma unroll
        for (int kk = 0; kk < SBK; ++kk) {
            float4 av = *(const float4*)&As[buf][kk][ty << 2];
            float4 wv = *(const float4*)&Wsh[buf][kk][tx << 2];
            float ar[4] = {av.x, av.y, av.z, av.w};
            float wr[4] = {wv.x, wv.y, wv.z, wv.w};
            #pragma unroll
            for (int i = 0; i < 4; ++i)
                #pragma unroll
                for (int j = 0; j < 4; ++j) acc[i][j] += ar[i] * wr[j];
        }
    };

    {
        float4 a0, a1;
        loadA(0, a0, a1);
        float4 w0 = *(const float4*)&W[(long)kW * N + colBase + nqW];
        float4 w1 = *(const float4*)&W[(long)(kW + 8) * N + colBase + nqW];
        stage(0, a0, a1, w0, w1);
    }
    __syncthreads();
    int cur = 0;
    int nt = K / SBK;
    for (int kt = 1; kt < nt; ++kt) {
        int k0 = kt * SBK;
        float4 a0, a1;
        loadA(k0, a0, a1);
        float4 w0 = *(const float4*)&W[(long)(k0 + kW) * N + colBase + nqW];
        float4 w1 = *(const float4*)&W[(long)(k0 + kW + 8) * N + colBase + nqW];
        compute(cur);
        stage(cur ^ 1, a0, a1, w0, w1);
        __syncthreads();
        cur ^= 1;
    }
    compute(cur);

    #pragma unroll
    for (int i = 0; i < 4; ++i) {
        int r = rowBase + (ty << 2) + i;
        if (r >= M) break;
        long cb = colBase + (tx << 2);
        float vv[4];
        #pragma unroll
        for (int j = 0; j < 4; ++j) {
            float v = acc[i][j] + bp[cb + j];
            if (HASB2) v += b2[cb + j];
            if (SP) {  // correctly-rounded fp32 softplus via fp64
                double vd = (double)v;
                v = (float)(log1p(exp(-fabs(vd))) + fmax(vd, 0.0));
            }
            if (HASRES) v += rp[(long)r * N + cb + j];
            vv[j] = v;
        }
        float4 o; o.x = vv[0]; o.y = vv[1]; o.z = vv[2]; o.w = vv[3];
        *(float4*)&C[(long)r * N + cb] = o;
    }
}

// ------------------------------------------------------------------
// fused depthwise conv (fwd + bwd) + SiLU
// ------------------------------------------------------------------
__global__ __launch_bounds__(256) void dwconv_k(const float* __restrict__ xp,
                                                const float* __restrict__ wf,
                                                const float* __restrict__ bf,
                                                const float* __restrict__ wb,
                                                const float* __restrict__ bb,
                                                float* __restrict__ xf,
                                                float* __restrict__ xb) {
    int idx = blockIdx.x * 256 + threadIdx.x;
    if (idx >= ROWS * EDIM) return;
    int e = idx % EDIM;
    int bm = idx / EDIM;
    int m = bm % MSEQ, b = bm / MSEQ;
    const float* base = xp + (long)b * MSEQ * EDIM + e;
    float xm1 = (m > 0)        ? base[(m - 1) * EDIM] : 0.f;
    float x0  =                  base[m * EDIM];
    float xp1 = (m < MSEQ - 1) ? base[(m + 1) * EDIM] : 0.f;
    float f = wf[e * 3 + 0] * xm1 + wf[e * 3 + 1] * x0 + wf[e * 3 + 2] * xp1 + bf[e];
    float r = wb[e * 3 + 0] * xp1 + wb[e * 3 + 1] * x0 + wb[e * 3 + 2] * xm1 + bb[e];
    xf[idx] = silu_f(f);
    xb[idx] = silu_f(r);
}

// ------------------------------------------------------------------
// SSM recurrence, PHASE-PARALLEL, bit-exact vs the sequential scan
// (same fp32 op order in every chain). One block per (b,e).
// ------------------------------------------------------------------
__global__ __launch_bounds__(256) void ssm_scan_k(const float* __restrict__ Bm,
                                                  const float* __restrict__ Cm,
                                                  const float* __restrict__ Dlt,
                                                  const float* __restrict__ xs,
                                                  const float* __restrict__ Apar,
                                                  float* __restrict__ y) {
#pragma clang fp contract(off)
    __shared__ float lgP[MSEQ][17];        // lg -> cumlog -> P
    __shared__ float trm[MSEQ][17];        // term -> h
    __shared__ signed char sgn[MSEQ][17];  // sa -> cumsign
    int be = blockIdx.x;
    int b = be / EDIM, e = be - b * EDIM;
    int t = threadIdx.x;
    int n0 = t & 15;                       // fixed per thread (256 % 16 == 0)
    float Ap = Apar[e * NSTATE + n0];
    const long dxBase = (long)b * MSEQ * EDIM + e;
    const long bcBase = (long)b * MSEQ * ENDIM + e * NSTATE;

    // phase 1
    for (int idx = t; idx < MSEQ * NSTATE; idx += 256) {
        int m = idx >> 4;
        float delta = Dlt[dxBase + (long)m * EDIM];
        float A = delta * Ap;                              // exact fp32 product
        float sa = (A > 0.f) ? 1.f : ((A < 0.f) ? -1.f : 0.f);
        float absA = fmaxf(fabsf(A), 1e-6f);
        lgP[m][n0] = (float)log((double)absA);             // CR fp32 log
        sgn[m][n0] = (signed char)sa;
    }
    __syncthreads();
    // phase 2: serial per n — identical add order to the sequential scan
    if (t < NSTATE) {
        float cl = 0.f, cs = 1.f;
        for (int m = 0; m < MSEQ; ++m) {
            float sa = (float)sgn[m][t];
            cs = cs * sa;
            cl = cl + lgP[m][t];
            lgP[m][t] = cl;
            sgn[m][t] = (signed char)cs;
        }
    }
    __syncthreads();
    // phase 3
    for (int idx = t; idx < MSEQ * NSTATE; idx += 256) {
        int m = idx >> 4;
        float cl = lgP[m][n0];
        float cs = (float)sgn[m][n0];
        float ex = (float)exp((double)cl);                 // CR fp32 exp
        float P = cs * ex;
        float tt = P + 1e-6f;                              // exact near-cancel
        float invP = 1.0f / tt;                            // IEEE fp32 div
        float delta = Dlt[dxBase + (long)m * EDIM];
        float xv = xs[dxBase + (long)m * EDIM];
        float Bv = Bm[bcBase + (long)m * ENDIM + n0];
        float Bfull = delta * Bv;
        float t1 = invP * Bfull;
        float t2 = t1 * xv;
        trm[m][n0] = t2;
        lgP[m][n0] = P;
    }
    __syncthreads();
    // phase 4: serial per n — identical add order
    if (t < NSTATE) {
        float S = 0.f;
        for (int m = 0; m < MSEQ; ++m) {
            S = S + trm[m][t];
            float h = lgP[m][t] * S;
            trm[m][t] = h;
        }
    }
    __syncthreads();
    // phase 5: numpy pairwise-16 tree (xor8, xor1, xor2, xor4; lane-0 order)
    for (int m = t; m < MSEQ; m += 256) {
        const float* cp = &Cm[bcBase + (long)m * ENDIM];
        float a[16];
        #pragma unroll
        for (int n = 0; n < 16; ++n) a[n] = trm[m][n] * cp[n];
        float b0 = a[0] + a[8],  b1 = a[1] + a[9];
        float b2v = a[2] + a[10], b3 = a[3] + a[11];
        float b4 = a[4] + a[12], b5 = a[5] + a[13];
        float b6 = a[6] + a[14], b7 = a[7] + a[15];
        float c0 = b0 + b1, c2 = b2v + b3, c4 = b4 + b5, c6 = b6 + b7;
        float d0 = c0 + c2, d4 = c4 + c6;
        y[dxBase + (long)m * EDIM] = d0 + d4;
    }
}

// ------------------------------------------------------------------
// combine: yc = (yf + yb) * silu(z)
// ------------------------------------------------------------------
__global__ __launch_bounds__(256) void combine_k(const float* __restrict__ yf,
                                                 const float* __restrict__ yb,
                                                 const float* __restrict__ z,
                                                 float* __restrict__ yc) {
    int idx = blockIdx.x * 256 + threadIdx.x;
    if (idx >= ROWS * EDIM) return;
    yc[idx] = (yf[idx] + yb[idx]) * silu_f(z[idx]);
}

extern "C" void kernel_launch(void* const* d_in, const int* in_sizes, int n_in,
                              void* d_out, int out_size, void* d_ws, size_t ws_size,
                              hipStream_t stream) {
    const float* img     = (const float*)d_in[0];
    const float* patch_w = (const float*)d_in[1];
    const float* patch_b = (const float*)d_in[2];
    const float* cls     = (const float*)d_in[3];
    const float* pos     = (const float*)d_in[4];
    const float* ln_g    = (const float*)d_in[5];
    const float* ln_b    = (const float*)d_in[6];
    const float* Wx  = (const float*)d_in[7];  const float* bx  = (const float*)d_in[8];
    const float* Wz  = (const float*)d_in[9];  const float* bz  = (const float*)d_in[10];
    const float* cwf = (const float*)d_in[11]; const float* cbf = (const float*)d_in[12];
    const float* cwb = (const float*)d_in[13]; const float* cbb = (const float*)d_in[14];
    const float* WBf = (const float*)d_in[15]; const float* bBf = (const float*)d_in[16];
    const float* WCf = (const float*)d_in[17]; const float* bCf = (const float*)d_in[18];
    const float* WDf = (const float*)d_in[19]; const float* bDf = (const float*)d_in[20];
    const float* Af  = (const float*)d_in[21]; const float* dbf = (const float*)d_in[22];
    const float* WBb = (const float*)d_in[23]; const float* bBb = (const float*)d_in[24];
    const float* WCb = (const float*)d_in[25]; const float* bCb = (const float*)d_in[26];
    const float* WDb = (const float*)d_in[27]; const float* bDb = (const float*)d_in[28];
    const float* Ab  = (const float*)d_in[29]; const float* dbb = (const float*)d_in[30];
    const float* Wout= (const float*)d_in[31]; const float* bout= (const float*)d_in[32];
    const float* ng  = (const float*)d_in[33]; const float* nb  = (const float*)d_in[34];

    float* ws = (float*)d_ws;
    float* xA   = ws;
    float* xB   = xA  + (size_t)ROWS * DDIM;
    float* xn   = xB  + (size_t)ROWS * DDIM;
    float* xp   = xn  + (size_t)ROWS * DDIM;
    float* zb   = xp  + (size_t)ROWS * EDIM;
    float* xfb  = zb  + (size_t)ROWS * EDIM;
    float* xbb  = xfb + (size_t)ROWS * EDIM;
    float* yfb  = xbb + (size_t)ROWS * EDIM;
    float* ybb  = yfb + (size_t)ROWS * EDIM;
    float* ycb  = ybb + (size_t)ROWS * EDIM;
    float* dlt  = ycb + (size_t)ROWS * EDIM;
    float* dlt2 = dlt + (size_t)ROWS * EDIM;
    float* Bmb  = dlt2 + (size_t)ROWS * EDIM;         // ROWS*ENDIM
    float* Cmb  = Bmb + (size_t)ROWS * ENDIM;
    // patchify scratch aliases the (not-yet-needed) B buffer
    float* patches = Bmb;                             // PROWS*PATCH_K
    float* xemb    = Bmb + (size_t)PROWS * PATCH_K;   // PROWS*DDIM

    // --- patch embedding ---
    patchify_k<<<(PROWS * PATCH_K + 255) / 256, 256, 0, stream>>>(img, patches);
    {   // 1568x192x768 GEMM
        dim3 g(DDIM / 32, (PROWS + 31) / 32, 1);
        gemm_s<false, false, false><<<g, 64, 0, stream>>>(
            patches, patch_w, patch_b, nullptr, nullptr, xemb,
            patches, patch_w, patch_b, nullptr, nullptr, xemb,
            PROWS, DDIM, PATCH_K);
    }
    assemble_k<<<(ROWS * DDIM + 255) / 256, 256, 0, stream>>>(xemb, cls, pos, xA);

    float* cur = xA; float* nxt = xB;
    for (int i = 0; i < LLAYERS; ++i) {
        layernorm_k<<<(ROWS + 3) / 4, 256, 0, stream>>>(cur, ln_g + i * DDIM, ln_b + i * DDIM, xn, ROWS);
        {   // Wx + Wz fused (shared A=xn)
            dim3 g(EDIM / 32, (ROWS + 31) / 32, 2);
            gemm_s<false, false, false><<<g, 64, 0, stream>>>(
                xn, Wx + (size_t)i * DDIM * EDIM, bx + i * EDIM, nullptr, nullptr, xp,
                xn, Wz + (size_t)i * DDIM * EDIM, bz + i * EDIM, nullptr, nullptr, zb,
                ROWS, EDIM, DDIM);
        }
        dwconv_k<<<(ROWS * EDIM + 255) / 256, 256, 0, stream>>>(xp, cwf + i * EDIM * 3, cbf + i * EDIM,
                                                                cwb + i * EDIM * 3, cbb + i * EDIM, xfb, xbb);
        {   // Df + Db fused (CR softplus epilogue)
            dim3 g(EDIM / 32, (ROWS + 31) / 32, 2);
            gemm_s<true, true, false><<<g, 64, 0, stream>>>(
                xfb, WDf + (size_t)i * EDIM * EDIM, bDf + i * EDIM, dbf + i * EDIM, nullptr, dlt,
                xbb, WDb + (size_t)i * EDIM * EDIM, bDb + i * EDIM, dbb + i * EDIM, nullptr, dlt2,
                ROWS, EDIM, EDIM);
        }
        {   // Bf + Cf fused z=2 (shared A=xfb; W set 18.8MB = L2-resident)
            dim3 g(ENDIM / 128, (ROWS + BM - 1) / BM, 2);
            gemm_big<<<g, 256, 0, stream>>>(
                xfb,
                WBf + (size_t)i * EDIM * ENDIM, bBf + i * ENDIM, Bmb,
                WCf + (size_t)i * EDIM * ENDIM, bCf + i * ENDIM, Cmb,
                ROWS, ENDIM, EDIM);
        }
        ssm_scan_k<<<BATCH * EDIM, 256, 0, stream>>>(Bmb, Cmb, dlt, xfb, Af + i * EDIM * NSTATE, yfb);
        {   // Bb + Cb fused z=2 (shared A=xbb)
            dim3 g(ENDIM / 128, (ROWS + BM - 1) / BM, 2);
            gemm_big<<<g, 256, 0, stream>>>(
                xbb,
                WBb + (size_t)i * EDIM * ENDIM, bBb + i * ENDIM, Bmb,
                WCb + (size_t)i * EDIM * ENDIM, bCb + i * ENDIM, Cmb,
                ROWS, ENDIM, EDIM);
        }
        ssm_scan_k<<<BATCH * EDIM, 256, 0, stream>>>(Bmb, Cmb, dlt2, xbb, Ab + i * EDIM * NSTATE, ybb);

        combine_k<<<(ROWS * EDIM + 255) / 256, 256, 0, stream>>>(yfb, ybb, zb, ycb);
        {   // Wout with residual
            dim3 g(DDIM / 32, (ROWS + 31) / 32, 1);
            gemm_s<false, false, true><<<g, 64, 0, stream>>>(
                ycb, Wout + (size_t)i * EDIM * DDIM, bout + i * DDIM, nullptr, cur, nxt,
                ycb, Wout + (size_t)i * EDIM * DDIM, bout + i * DDIM, nullptr, cur, nxt,
                ROWS, DDIM, EDIM);
        }
        float* t = cur; cur = nxt; nxt = t;
    }
    layernorm_k<<<(ROWS + 3) / 4, 256, 0, stream>>>(cur, ng, nb, (float*)d_out, ROWS);
}

// Round 10
// 1208.768 us; speedup vs baseline: 1.4161x; 1.4161x over previous
//
#include <hip/hip_runtime.h>
#include <hip/hip_bf16.h>
#include <math.h>

// ---- problem constants ----
#define BATCH   8
#define C_IN    3
#define IMG_SZ  224
#define P_SZ    16
#define NPATCH  196                 // (224/16)^2
#define MSEQ    197                 // NPATCH + cls
#define DDIM    192
#define EDIM    384
#define NSTATE  16
#define ENDIM   (EDIM*NSTATE)       // 6144
#define LLAYERS 2
#define ROWS    (BATCH*MSEQ)        // 1576
#define PROWS   (BATCH*NPATCH)      // 1568
#define PATCH_K (C_IN*P_SZ*P_SZ)    // 768

// precise silu (enters the scan only linearly)
__device__ __forceinline__ float silu_f(float x) { return x / (1.f + expf(-x)); }

// ------------------------------------------------------------------
// patchify: img (B,3,224,224) -> patches (PROWS, 768)
// ------------------------------------------------------------------
__global__ __launch_bounds__(256) void patchify_k(const float* __restrict__ img,
                                                  float* __restrict__ out) {
    int idx = blockIdx.x * 256 + threadIdx.x;
    if (idx >= PROWS * PATCH_K) return;
    int r = idx / PATCH_K, col = idx - r * PATCH_K;
    int b = r / NPATCH, p = r - b * NPATCH;
    int ph = p / 14, pw = p - ph * 14;
    int c = col >> 8, rem = col & 255, py = rem >> 4, px = rem & 15;
    out[idx] = img[((b * C_IN + c) * IMG_SZ + ph * P_SZ + py) * IMG_SZ + pw * P_SZ + px];
}

// ------------------------------------------------------------------
// assemble x = concat(cls, xemb) + pos   -> (B, MSEQ, DDIM)
// ------------------------------------------------------------------
__global__ __launch_bounds__(256) void assemble_k(const float* __restrict__ xemb,
                                                  const float* __restrict__ cls,
                                                  const float* __restrict__ pos,
                                                  float* __restrict__ x) {
    int idx = blockIdx.x * 256 + threadIdx.x;
    if (idx >= ROWS * DDIM) return;
    int d = idx % DDIM;
    int bm = idx / DDIM;
    int m = bm % MSEQ, b = bm / MSEQ;
    float v;
    if (m == 0) v = cls[d];
    else        v = xemb[((b * NPATCH) + (m - 1)) * DDIM + d];
    x[idx] = v + pos[m * DDIM + d];
}

// ------------------------------------------------------------------
// layernorm over last dim (DDIM=192), one wave per row
// ------------------------------------------------------------------
__global__ __launch_bounds__(256) void layernorm_k(const float* __restrict__ x,
                                                   const float* __restrict__ g,
                                                   const float* __restrict__ b,
                                                   float* __restrict__ o, int nrows) {
    int wave = threadIdx.x >> 6;
    int lane = threadIdx.x & 63;
    int row = blockIdx.x * 4 + wave;
    if (row >= nrows) return;
    const float* xr = x + (long)row * DDIM;
    float v0 = xr[lane], v1 = xr[lane + 64], v2 = xr[lane + 128];
    float s = v0 + v1 + v2;
    #pragma unroll
    for (int off = 1; off < 64; off <<= 1) s += __shfl_xor(s, off);
    float mu = s * (1.f / 192.f);
    float d0 = v0 - mu, d1 = v1 - mu, d2 = v2 - mu;
    float q = d0 * d0 + d1 * d1 + d2 * d2;
    #pragma unroll
    for (int off = 1; off < 64; off <<= 1) q += __shfl_xor(q, off);
    float inv = rsqrtf(q * (1.f / 192.f) + 1e-5f);
    float* orow = o + (long)row * DDIM;
    orow[lane]       = d0 * inv * g[lane]       + b[lane];
    orow[lane + 64]  = d1 * inv * g[lane + 64]  + b[lane + 64];
    orow[lane + 128] = d2 * inv * g[lane + 128] + b[lane + 128];
}

// ------------------------------------------------------------------
// BIG fp32 GEMM for the B/C projections (N=6144), tile 128x128,
// 8x8/thread, 256 threads. ROUND-6 STRUCTURE (best measured: 195us,
// FETCH 33MB): single LDS buffer, loads staged IMMEDIATELY (wave
// stalls on vmcnt each K-step -> co-resident blocks stay in lockstep
// -> W panels re-referenced within L2 retention window). Reg-staged
// prefetch variants (r8/r9) de-synchronized blocks -> 16x W/A
// over-fetch from HBM (FETCH 521MB, 322us). Keep 2 barriers/K-step.
// gridDim.z=2 selects {W0->C0, W1->C1} with the SAME A (z=4 would
// also blow the L2 working set: round-8 lesson).
// ------------------------------------------------------------------
#define BM 128
#define BK 16
__global__ __launch_bounds__(256) void gemm_big(
        const float* __restrict__ A,
        const float* __restrict__ W0, const float* __restrict__ b0, float* __restrict__ C0,
        const float* __restrict__ W1, const float* __restrict__ b1, float* __restrict__ C1,
        int M, int N, int K) {
    const float* W    = blockIdx.z ? W1 : W0;
    const float* bias = blockIdx.z ? b1 : b0;
    float*       C    = blockIdx.z ? C1 : C0;
    __shared__ float As[BK][BM + 4];
    __shared__ float Ws[2][BK][64];
    int t = threadIdx.x;
    int tx = t & 15, ty = t >> 4;
    long colBase = (long)blockIdx.x * 128;
    int rowBase = blockIdx.y * BM;
    float acc[8][8] = {};
    int a_m = t >> 1, a_k = (t & 1) << 3;      // A: 2 float4 per thread
    int w_k = t >> 4, w_n = (t & 15) << 2;     // W: 1 float4 per panel per thread
    for (int k0 = 0; k0 < K; k0 += BK) {
        int ar = rowBase + a_m;
        float4 av0 = make_float4(0.f, 0.f, 0.f, 0.f), av1 = av0;
        if (ar < M) {
            const float* ap = &A[(long)ar * K + k0 + a_k];
            av0 = *(const float4*)ap;
            av1 = *(const float4*)(ap + 4);
        }
        As[a_k + 0][a_m] = av0.x; As[a_k + 1][a_m] = av0.y;
        As[a_k + 2][a_m] = av0.z; As[a_k + 3][a_m] = av0.w;
        As[a_k + 4][a_m] = av1.x; As[a_k + 5][a_m] = av1.y;
        As[a_k + 6][a_m] = av1.z; As[a_k + 7][a_m] = av1.w;
        #pragma unroll
        for (int hh = 0; hh < 2; ++hh)
            *(float4*)&Ws[hh][w_k][w_n] =
                *(const float4*)&W[(long)(k0 + w_k) * N + colBase + hh * 64 + w_n];
        __syncthreads();
        #pragma unroll
        for (int kk = 0; kk < BK; ++kk) {
            float4 a0 = *(const float4*)&As[kk][ty << 3];
            float4 a1 = *(const float4*)&As[kk][(ty << 3) + 4];
            float ar8[8] = {a0.x, a0.y, a0.z, a0.w, a1.x, a1.y, a1.z, a1.w};
            #pragma unroll
            for (int hh = 0; hh < 2; ++hh) {
                float4 w = *(const float4*)&Ws[hh][kk][tx << 2];
                float wr[4] = {w.x, w.y, w.z, w.w};
                #pragma unroll
                for (int i = 0; i < 8; ++i)
                    #pragma unroll
                    for (int j = 0; j < 4; ++j)
                        acc[i][hh * 4 + j] += ar8[i] * wr[j];
            }
        }
        __syncthreads();
    }
    #pragma unroll
    for (int i = 0; i < 8; ++i) {
        int r = rowBase + (ty << 3) + i;
        if (r >= M) break;
        #pragma unroll
        for (int hh = 0; hh < 2; ++hh) {
            long cb = colBase + hh * 64 + (tx << 2);
            float4 o;
            o.x = acc[i][hh * 4 + 0] + bias[cb + 0];
            o.y = acc[i][hh * 4 + 1] + bias[cb + 1];
            o.z = acc[i][hh * 4 + 2] + bias[cb + 2];
            o.w = acc[i][hh * 4 + 3] + bias[cb + 3];
            *(float4*)&C[(long)r * N + cb] = o;
        }
    }
}

// ------------------------------------------------------------------
// SMALL fp32 GEMM: one WAVE per 32x32 tile, 4x4/thread, double-
// buffered LDS. gridDim.z selects two independent sets (Wx+Wz, Df+Db).
// SP = correctly-rounded softplus epilogue. k-ascending FMA order.
// ------------------------------------------------------------------
#define SBK 16
template<bool SP, bool HASB2, bool HASRES>
__global__ __launch_bounds__(64) void gemm_s(const float* __restrict__ A0,
                                             const float* __restrict__ W0,
                                             const float* __restrict__ b10,
                                             const float* __restrict__ b20,
                                             const float* __restrict__ r0,
                                             float* __restrict__ C0,
                                             const float* __restrict__ A1,
                                             const float* __restrict__ W1,
                                             const float* __restrict__ b11,
                                             const float* __restrict__ b21,
                                             const float* __restrict__ r1,
                                             float* __restrict__ C1,
                                             int M, int N, int K) {
    const float* A  = blockIdx.z ? A1  : A0;
    const float* W  = blockIdx.z ? W1  : W0;
    const float* bp = blockIdx.z ? b11 : b10;
    const float* b2 = blockIdx.z ? b21 : b20;
    const float* rp = blockIdx.z ? r1  : r0;
    float*       C  = blockIdx.z ? C1  : C0;
    __shared__ float As[2][SBK][36];
    __shared__ float Wsh[2][SBK][36];
    int t = threadIdx.x;            // 0..63
    int tx = t & 7, ty = t >> 3;
    int rowBase = blockIdx.y * 32;
    long colBase = (long)blockIdx.x * 32;
    int rA = t >> 2, kqA = (t & 3) << 2;
    int kW = t >> 3, nqW = (t & 7) << 2;
    float acc[4][4] = {};
    int r0i = rowBase + rA, r1i = r0i + 16;

    auto loadA = [&](int k0, float4& a0, float4& a1) {
        a0 = make_float4(0.f,0.f,0.f,0.f); a1 = a0;
        if (r0i < M) a0 = *(const float4*)&A[(long)r0i * K + k0 + kqA];
        if (r1i < M) a1 = *(const float4*)&A[(long)r1i * K + k0 + kqA];
    };
    auto stage = [&](int buf, float4 a0, float4 a1, float4 w0, float4 w1) {
        As[buf][kqA + 0][rA] = a0.x; As[buf][kqA + 1][rA] = a0.y;
        As[buf][kqA + 2][rA] = a0.z; As[buf][kqA + 3][rA] = a0.w;
        As[buf][kqA + 0][rA + 16] = a1.x; As[buf][kqA + 1][rA + 16] = a1.y;
        As[buf][kqA + 2][rA + 16] = a1.z; As[buf][kqA + 3][rA + 16] = a1.w;
        *(float4*)&Wsh[buf][kW][nqW]     = w0;
        *(float4*)&Wsh[buf][kW + 8][nqW] = w1;
    };
    auto compute = [&](int buf) {
        #pragma unroll
        for (int kk = 0; kk < SBK; ++kk) {
            float4 av = *(const float4*)&As[buf][kk][ty << 2];
            float4 wv = *(const float4*)&Wsh[buf][kk][tx << 2];
            float ar[4] = {av.x, av.y, av.z, av.w};
            float wr[4] = {wv.x, wv.y, wv.z, wv.w};
            #pragma unroll
            for (int i = 0; i < 4; ++i)
                #pragma unroll
                for (int j = 0; j < 4; ++j) acc[i][j] += ar[i] * wr[j];
        }
    };

    {
        float4 a0, a1;
        loadA(0, a0, a1);
        float4 w0 = *(const float4*)&W[(long)kW * N + colBase + nqW];
        float4 w1 = *(const float4*)&W[(long)(kW + 8) * N + colBase + nqW];
        stage(0, a0, a1, w0, w1);
    }
    __syncthreads();
    int cur = 0;
    int nt = K / SBK;
    for (int kt = 1; kt < nt; ++kt) {
        int k0 = kt * SBK;
        float4 a0, a1;
        loadA(k0, a0, a1);
        float4 w0 = *(const float4*)&W[(long)(k0 + kW) * N + colBase + nqW];
        float4 w1 = *(const float4*)&W[(long)(k0 + kW + 8) * N + colBase + nqW];
        compute(cur);
        stage(cur ^ 1, a0, a1, w0, w1);
        __syncthreads();
        cur ^= 1;
    }
    compute(cur);

    #pragma unroll
    for (int i = 0; i < 4; ++i) {
        int r = rowBase + (ty << 2) + i;
        if (r >= M) break;
        long cb = colBase + (tx << 2);
        float vv[4];
        #pragma unroll
        for (int j = 0; j < 4; ++j) {
            float v = acc[i][j] + bp[cb + j];
            if (HASB2) v += b2[cb + j];
            if (SP) {  // correctly-rounded fp32 softplus via fp64
                double vd = (double)v;
                v = (float)(log1p(exp(-fabs(vd))) + fmax(vd, 0.0));
            }
            if (HASRES) v += rp[(long)r * N + cb + j];
            vv[j] = v;
        }
        float4 o; o.x = vv[0]; o.y = vv[1]; o.z = vv[2]; o.w = vv[3];
        *(float4*)&C[(long)r * N + cb] = o;
    }
}

// ------------------------------------------------------------------
// fused depthwise conv (fwd + bwd) + SiLU
// ------------------------------------------------------------------
__global__ __launch_bounds__(256) void dwconv_k(const float* __restrict__ xp,
                                                const float* __restrict__ wf,
                                                const float* __restrict__ bf,
                                                const float* __restrict__ wb,
                                                const float* __restrict__ bb,
                                                float* __restrict__ xf,
                                                float* __restrict__ xb) {
    int idx = blockIdx.x * 256 + threadIdx.x;
    if (idx >= ROWS * EDIM) return;
    int e = idx % EDIM;
    int bm = idx / EDIM;
    int m = bm % MSEQ, b = bm / MSEQ;
    const float* base = xp + (long)b * MSEQ * EDIM + e;
    float xm1 = (m > 0)        ? base[(m - 1) * EDIM] : 0.f;
    float x0  =                  base[m * EDIM];
    float xp1 = (m < MSEQ - 1) ? base[(m + 1) * EDIM] : 0.f;
    float f = wf[e * 3 + 0] * xm1 + wf[e * 3 + 1] * x0 + wf[e * 3 + 2] * xp1 + bf[e];
    float r = wb[e * 3 + 0] * xp1 + wb[e * 3 + 1] * x0 + wb[e * 3 + 2] * xm1 + bb[e];
    xf[idx] = silu_f(f);
    xb[idx] = silu_f(r);
}

// ------------------------------------------------------------------
// SSM recurrence, PHASE-PARALLEL, bit-exact vs the sequential scan
// (same fp32 op order in every chain). One block per (b,e).
// ------------------------------------------------------------------
__global__ __launch_bounds__(256) void ssm_scan_k(const float* __restrict__ Bm,
                                                  const float* __restrict__ Cm,
                                                  const float* __restrict__ Dlt,
                                                  const float* __restrict__ xs,
                                                  const float* __restrict__ Apar,
                                                  float* __restrict__ y) {
#pragma clang fp contract(off)
    __shared__ float lgP[MSEQ][17];        // lg -> cumlog -> P
    __shared__ float trm[MSEQ][17];        // term -> h
    __shared__ signed char sgn[MSEQ][17];  // sa -> cumsign
    int be = blockIdx.x;
    int b = be / EDIM, e = be - b * EDIM;
    int t = threadIdx.x;
    int n0 = t & 15;                       // fixed per thread (256 % 16 == 0)
    float Ap = Apar[e * NSTATE + n0];
    const long dxBase = (long)b * MSEQ * EDIM + e;
    const long bcBase = (long)b * MSEQ * ENDIM + e * NSTATE;

    // phase 1
    for (int idx = t; idx < MSEQ * NSTATE; idx += 256) {
        int m = idx >> 4;
        float delta = Dlt[dxBase + (long)m * EDIM];
        float A = delta * Ap;                              // exact fp32 product
        float sa = (A > 0.f) ? 1.f : ((A < 0.f) ? -1.f : 0.f);
        float absA = fmaxf(fabsf(A), 1e-6f);
        lgP[m][n0] = (float)log((double)absA);             // CR fp32 log
        sgn[m][n0] = (signed char)sa;
    }
    __syncthreads();
    // phase 2: serial per n — identical add order to the sequential scan
    if (t < NSTATE) {
        float cl = 0.f, cs = 1.f;
        for (int m = 0; m < MSEQ; ++m) {
            float sa = (float)sgn[m][t];
            cs = cs * sa;
            cl = cl + lgP[m][t];
            lgP[m][t] = cl;
            sgn[m][t] = (signed char)cs;
        }
    }
    __syncthreads();
    // phase 3
    for (int idx = t; idx < MSEQ * NSTATE; idx += 256) {
        int m = idx >> 4;
        float cl = lgP[m][n0];
        float cs = (float)sgn[m][n0];
        float ex = (float)exp((double)cl);                 // CR fp32 exp
        float P = cs * ex;
        float tt = P + 1e-6f;                              // exact near-cancel
        float invP = 1.0f / tt;                            // IEEE fp32 div
        float delta = Dlt[dxBase + (long)m * EDIM];
        float xv = xs[dxBase + (long)m * EDIM];
        float Bv = Bm[bcBase + (long)m * ENDIM + n0];
        float Bfull = delta * Bv;
        float t1 = invP * Bfull;
        float t2 = t1 * xv;
        trm[m][n0] = t2;
        lgP[m][n0] = P;
    }
    __syncthreads();
    // phase 4: serial per n — identical add order
    if (t < NSTATE) {
        float S = 0.f;
        for (int m = 0; m < MSEQ; ++m) {
            S = S + trm[m][t];
            float h = lgP[m][t] * S;
            trm[m][t] = h;
        }
    }
    __syncthreads();
    // phase 5: numpy pairwise-16 tree (xor8, xor1, xor2, xor4; lane-0 order)
    for (int m = t; m < MSEQ; m += 256) {
        const float* cp = &Cm[bcBase + (long)m * ENDIM];
        float a[16];
        #pragma unroll
        for (int n = 0; n < 16; ++n) a[n] = trm[m][n] * cp[n];
        float b0 = a[0] + a[8],  b1 = a[1] + a[9];
        float b2v = a[2] + a[10], b3 = a[3] + a[11];
        float b4 = a[4] + a[12], b5 = a[5] + a[13];
        float b6 = a[6] + a[14], b7 = a[7] + a[15];
        float c0 = b0 + b1, c2 = b2v + b3, c4 = b4 + b5, c6 = b6 + b7;
        float d0 = c0 + c2, d4 = c4 + c6;
        y[dxBase + (long)m * EDIM] = d0 + d4;
    }
}

// ------------------------------------------------------------------
// combine: yc = (yf + yb) * silu(z)
// ------------------------------------------------------------------
__global__ __launch_bounds__(256) void combine_k(const float* __restrict__ yf,
                                                 const float* __restrict__ yb,
                                                 const float* __restrict__ z,
                                                 float* __restrict__ yc) {
    int idx = blockIdx.x * 256 + threadIdx.x;
    if (idx >= ROWS * EDIM) return;
    yc[idx] = (yf[idx] + yb[idx]) * silu_f(z[idx]);
}

extern "C" void kernel_launch(void* const* d_in, const int* in_sizes, int n_in,
                              void* d_out, int out_size, void* d_ws, size_t ws_size,
                              hipStream_t stream) {
    const float* img     = (const float*)d_in[0];
    const float* patch_w = (const float*)d_in[1];
    const float* patch_b = (const float*)d_in[2];
    const float* cls     = (const float*)d_in[3];
    const float* pos     = (const float*)d_in[4];
    const float* ln_g    = (const float*)d_in[5];
    const float* ln_b    = (const float*)d_in[6];
    const float* Wx  = (const float*)d_in[7];  const float* bx  = (const float*)d_in[8];
    const float* Wz  = (const float*)d_in[9];  const float* bz  = (const float*)d_in[10];
    const float* cwf = (const float*)d_in[11]; const float* cbf = (const float*)d_in[12];
    const float* cwb = (const float*)d_in[13]; const float* cbb = (const float*)d_in[14];
    const float* WBf = (const float*)d_in[15]; const float* bBf = (const float*)d_in[16];
    const float* WCf = (const float*)d_in[17]; const float* bCf = (const float*)d_in[18];
    const float* WDf = (const float*)d_in[19]; const float* bDf = (const float*)d_in[20];
    const float* Af  = (const float*)d_in[21]; const float* dbf = (const float*)d_in[22];
    const float* WBb = (const float*)d_in[23]; const float* bBb = (const float*)d_in[24];
    const float* WCb = (const float*)d_in[25]; const float* bCb = (const float*)d_in[26];
    const float* WDb = (const float*)d_in[27]; const float* bDb = (const float*)d_in[28];
    const float* Ab  = (const float*)d_in[29]; const float* dbb = (const float*)d_in[30];
    const float* Wout= (const float*)d_in[31]; const float* bout= (const float*)d_in[32];
    const float* ng  = (const float*)d_in[33]; const float* nb  = (const float*)d_in[34];

    float* ws = (float*)d_ws;
    float* xA   = ws;
    float* xB   = xA  + (size_t)ROWS * DDIM;
    float* xn   = xB  + (size_t)ROWS * DDIM;
    float* xp   = xn  + (size_t)ROWS * DDIM;
    float* zb   = xp  + (size_t)ROWS * EDIM;
    float* xfb  = zb  + (size_t)ROWS * EDIM;
    float* xbb  = xfb + (size_t)ROWS * EDIM;
    float* yfb  = xbb + (size_t)ROWS * EDIM;
    float* ybb  = yfb + (size_t)ROWS * EDIM;
    float* ycb  = ybb + (size_t)ROWS * EDIM;
    float* dlt  = ycb + (size_t)ROWS * EDIM;
    float* dlt2 = dlt + (size_t)ROWS * EDIM;
    float* Bmb  = dlt2 + (size_t)ROWS * EDIM;         // ROWS*ENDIM
    float* Cmb  = Bmb + (size_t)ROWS * ENDIM;
    // patchify scratch aliases the (not-yet-needed) B buffer
    float* patches = Bmb;                             // PROWS*PATCH_K
    float* xemb    = Bmb + (size_t)PROWS * PATCH_K;   // PROWS*DDIM

    // --- patch embedding ---
    patchify_k<<<(PROWS * PATCH_K + 255) / 256, 256, 0, stream>>>(img, patches);
    {   // 1568x192x768 GEMM
        dim3 g(DDIM / 32, (PROWS + 31) / 32, 1);
        gemm_s<false, false, false><<<g, 64, 0, stream>>>(
            patches, patch_w, patch_b, nullptr, nullptr, xemb,
            patches, patch_w, patch_b, nullptr, nullptr, xemb,
            PROWS, DDIM, PATCH_K);
    }
    assemble_k<<<(ROWS * DDIM + 255) / 256, 256, 0, stream>>>(xemb, cls, pos, xA);

    float* cur = xA; float* nxt = xB;
    for (int i = 0; i < LLAYERS; ++i) {
        layernorm_k<<<(ROWS + 3) / 4, 256, 0, stream>>>(cur, ln_g + i * DDIM, ln_b + i * DDIM, xn, ROWS);
        {   // Wx + Wz fused (shared A=xn)
            dim3 g(EDIM / 32, (ROWS + 31) / 32, 2);
            gemm_s<false, false, false><<<g, 64, 0, stream>>>(
                xn, Wx + (size_t)i * DDIM * EDIM, bx + i * EDIM, nullptr, nullptr, xp,
                xn, Wz + (size_t)i * DDIM * EDIM, bz + i * EDIM, nullptr, nullptr, zb,
                ROWS, EDIM, DDIM);
        }
        dwconv_k<<<(ROWS * EDIM + 255) / 256, 256, 0, stream>>>(xp, cwf + i * EDIM * 3, cbf + i * EDIM,
                                                                cwb + i * EDIM * 3, cbb + i * EDIM, xfb, xbb);
        {   // Df + Db fused (CR softplus epilogue)
            dim3 g(EDIM / 32, (ROWS + 31) / 32, 2);
            gemm_s<true, true, false><<<g, 64, 0, stream>>>(
                xfb, WDf + (size_t)i * EDIM * EDIM, bDf + i * EDIM, dbf + i * EDIM, nullptr, dlt,
                xbb, WDb + (size_t)i * EDIM * EDIM, bDb + i * EDIM, dbb + i * EDIM, nullptr, dlt2,
                ROWS, EDIM, EDIM);
        }
        {   // Bf + Cf fused z=2 (shared A=xfb; W set 18.8MB = L2-resident)
            dim3 g(ENDIM / 128, (ROWS + BM - 1) / BM, 2);
            gemm_big<<<g, 256, 0, stream>>>(
                xfb,
                WBf + (size_t)i * EDIM * ENDIM, bBf + i * ENDIM, Bmb,
                WCf + (size_t)i * EDIM * ENDIM, bCf + i * ENDIM, Cmb,
                ROWS, ENDIM, EDIM);
        }
        ssm_scan_k<<<BATCH * EDIM, 256, 0, stream>>>(Bmb, Cmb, dlt, xfb, Af + i * EDIM * NSTATE, yfb);
        {   // Bb + Cb fused z=2 (shared A=xbb)
            dim3 g(ENDIM / 128, (ROWS + BM - 1) / BM, 2);
            gemm_big<<<g, 256, 0, stream>>>(
                xbb,
                WBb + (size_t)i * EDIM * ENDIM, bBb + i * ENDIM, Bmb,
                WCb + (size_t)i * EDIM * ENDIM, bCb + i * ENDIM, Cmb,
                ROWS, ENDIM, EDIM);
        }
        ssm_scan_k<<<BATCH * EDIM, 256, 0, stream>>>(Bmb, Cmb, dlt2, xbb, Ab + i * EDIM * NSTATE, ybb);

        combine_k<<<(ROWS * EDIM + 255) / 256, 256, 0, stream>>>(yfb, ybb, zb, ycb);
        {   // Wout with residual
            dim3 g(DDIM / 32, (ROWS + 31) / 32, 1);
            gemm_s<false, false, true><<<g, 64, 0, stream>>>(
                ycb, Wout + (size_t)i * EDIM * DDIM, bout + i * DDIM, nullptr, cur, nxt,
                ycb, Wout + (size_t)i * EDIM * DDIM, bout + i * DDIM, nullptr, cur, nxt,
                ROWS, DDIM, EDIM);
        }
        float* t = cur; cur = nxt; nxt = t;
    }
    layernorm_k<<<(ROWS + 3) / 4, 256, 0, stream>>>(cur, ng, nb, (float*)d_out, ROWS);
}